// Round 1
// baseline (828.829 us; speedup 1.0000x reference)
//
#include <hip/hip_runtime.h>
#include <stdint.h>

#define HW 65536   // 256*256
#define W_ 256
#define C_ 64
#define NPK 36     // u32 per LDS row = 72 bf16 (64 used + 8 pad) -> 144B row stride, 16B aligned

__device__ inline uint32_t pack_bf16(float lo, float hi) {
  uint32_t ul = __float_as_uint(lo);
  uint32_t uh = __float_as_uint(hi);
  ul = (ul + 0x7fffu + ((ul >> 16) & 1u)) >> 16;
  uh = (uh + 0x7fffu + ((uh >> 16) & 1u)) >> 16;
  return ul | (uh << 16);
}

// 1x1 conv for one output pixel-column: out[o] = sum_c W[o,c]*X[c] (+ coord terms) + bias[o] + mod[o]*E[o]
// Writes the 64 outputs as packed bf16 into this thread's LDS row.
__device__ inline void conv_to_lds(
    const float* __restrict__ X,    // &x[side_b][0][hh][i], channel stride HW
    const float* __restrict__ E,    // &tr_or_re[side_b][0][hh][i]
    const float* __restrict__ Wm, int ldw,
    const float* __restrict__ bias,
    const float* __restrict__ mod,  // beta1 or gamma1 (64)
    float yy, float rr, int hasCoord,
    uint32_t* __restrict__ ldsRow)
{
  float xv[C_];
  #pragma unroll
  for (int c = 0; c < C_; ++c) xv[c] = X[(size_t)c * HW];
  float pend = 0.f;
  for (int o = 0; o < C_; ++o) {
    const float* wr = Wm + o * ldw;
    float a0 = bias[o], a1 = 0.f, a2 = 0.f, a3 = 0.f;
    #pragma unroll
    for (int c = 0; c < C_; c += 4) {
      a0 = fmaf(wr[c],   xv[c],   a0);
      a1 = fmaf(wr[c+1], xv[c+1], a1);
      a2 = fmaf(wr[c+2], xv[c+2], a2);
      a3 = fmaf(wr[c+3], xv[c+3], a3);
    }
    float a = (a0 + a1) + (a2 + a3);
    if (hasCoord) a += wr[64] * yy + wr[65] * rr;
    a = fmaf(mod[o], E[(size_t)o * HW], a);
    if (o & 1) ldsRow[o >> 1] = pack_bf16(pend, a);
    else       pend = a;
  }
}

__device__ inline void read_row(const uint32_t* __restrict__ row, float v[C_]) {
  const uint4* r4 = (const uint4*)row;
  #pragma unroll
  for (int t = 0; t < 8; ++t) {
    uint4 u = r4[t];
    v[8*t+0] = __uint_as_float(u.x << 16);
    v[8*t+1] = __uint_as_float(u.x & 0xffff0000u);
    v[8*t+2] = __uint_as_float(u.y << 16);
    v[8*t+3] = __uint_as_float(u.y & 0xffff0000u);
    v[8*t+4] = __uint_as_float(u.z << 16);
    v[8*t+5] = __uint_as_float(u.z & 0xffff0000u);
    v[8*t+6] = __uint_as_float(u.w << 16);
    v[8*t+7] = __uint_as_float(u.w & 0xffff0000u);
  }
}

__device__ inline float dot_row_q(const uint32_t* __restrict__ row, const float q[C_]) {
  const uint4* r4 = (const uint4*)row;
  float s0 = 0.f, s1 = 0.f, s2 = 0.f, s3 = 0.f;
  #pragma unroll
  for (int t = 0; t < 8; ++t) {
    uint4 u = r4[t];
    s0 = fmaf(q[8*t+0], __uint_as_float(u.x << 16),         s0);
    s1 = fmaf(q[8*t+1], __uint_as_float(u.x & 0xffff0000u), s1);
    s2 = fmaf(q[8*t+2], __uint_as_float(u.y << 16),         s2);
    s3 = fmaf(q[8*t+3], __uint_as_float(u.y & 0xffff0000u), s3);
    s0 = fmaf(q[8*t+4], __uint_as_float(u.z << 16),         s0);
    s1 = fmaf(q[8*t+5], __uint_as_float(u.z & 0xffff0000u), s1);
    s2 = fmaf(q[8*t+6], __uint_as_float(u.w << 16),         s2);
    s3 = fmaf(q[8*t+7], __uint_as_float(u.w & 0xffff0000u), s3);
  }
  return (s0 + s1) + (s2 + s3);
}

__global__ __launch_bounds__(256, 2) void SCAM_73151882985874_kernel(
    const float* __restrict__ x, const float* __restrict__ res_enc,
    const float* __restrict__ tr_feat,
    const float* __restrict__ Wl1, const float* __restrict__ bl1,
    const float* __restrict__ Wr1, const float* __restrict__ br1,
    const float* __restrict__ Wl2, const float* __restrict__ bl2,
    const float* __restrict__ Wr2, const float* __restrict__ br2,
    const float* __restrict__ beta1, const float* __restrict__ gamma1,
    const float* __restrict__ beta3, const float* __restrict__ gamma3,
    float* __restrict__ out)
{
  __shared__ uint32_t A[W_][NPK];
  __shared__ uint32_t B[W_][NPK];

  const int i  = threadIdx.x;
  const int bh = blockIdx.x;
  const int bb = bh >> 8;    // 0..1 : left-batch index
  const int hh = bh & 255;

  const float yy = (float)hh * (2.0f / 255.0f) - 1.0f;
  const float rr = fabsf(yy - 0.5f);
  const float scale = 0.125f;  // 64^-0.5

  const size_t base_l = (size_t)bb * (C_ * (size_t)HW) + (size_t)hh * W_ + i;
  const size_t base_r = base_l + 2ull * C_ * HW;
  const float* xl  = x + base_l;       const float* xr  = x + base_r;
  const float* rel = res_enc + base_l; const float* rer = res_enc + base_r;
  const float* trl = tr_feat + base_l; const float* trr = tr_feat + base_r;

  // Phase 1: Q -> A, S -> B   (Q = Wl1*addcoords(x_l)+bl1+beta1*tr_l, per-column)
  conv_to_lds(xl, trl, Wl1, 66, bl1, beta1, yy, rr, 1, A[i]);
  conv_to_lds(xr, trr, Wr1, 66, br1, beta1, yy, rr, 1, B[i]);
  __syncthreads();

  // Phase 2a: row-softmax stats (M_r2l row i): s_ij over j<=i
  float m1 = -1e30f, z1 = 0.f;
  {
    float q[C_]; read_row(A[i], q);
    for (int j = 0; j <= i; ++j) {
      float s  = scale * dot_row_q(B[j], q);
      float nm = fmaxf(m1, s);
      z1 = z1 * __expf(m1 - nm) + __expf(s - nm);
      m1 = nm;
    }
  }
  // Phase 2b: col-softmax stats (M_l2r row i): s_ji over j>=i; keep Scol for out_R
  float m2 = -1e30f, z2 = 0.f;
  float sc[C_]; read_row(B[i], sc);
  for (int j = i; j < W_; ++j) {
    float s  = scale * dot_row_q(A[j], sc);
    float nm = fmaxf(m2, s);
    z2 = z2 * __expf(m2 - nm) + __expf(s - nm);
    m2 = nm;
  }
  __syncthreads();

  // Phase 3: bufL -> B (overwrite S; S column kept in sc[])
  conv_to_lds(xl, rel, Wl2, 64, bl2, gamma1, 0.f, 0.f, 0, B[i]);
  __syncthreads();

  // Phase 4: out_R[c,i] = x_r + gamma3 * (sum_{j>=i} exp(s_ji - m2) * bufL[c,j]) / z2
  {
    float acc[C_];
    #pragma unroll
    for (int c = 0; c < C_; ++c) acc[c] = 0.f;
    for (int j = i; j < W_; ++j) {
      float s = scale * dot_row_q(A[j], sc);
      float p = __expf(s - m2);
      const uint4* r4 = (const uint4*)B[j];
      #pragma unroll
      for (int t = 0; t < 8; ++t) {
        uint4 u = r4[t];
        acc[8*t+0] = fmaf(p, __uint_as_float(u.x << 16),         acc[8*t+0]);
        acc[8*t+1] = fmaf(p, __uint_as_float(u.x & 0xffff0000u), acc[8*t+1]);
        acc[8*t+2] = fmaf(p, __uint_as_float(u.y << 16),         acc[8*t+2]);
        acc[8*t+3] = fmaf(p, __uint_as_float(u.y & 0xffff0000u), acc[8*t+3]);
        acc[8*t+4] = fmaf(p, __uint_as_float(u.z << 16),         acc[8*t+4]);
        acc[8*t+5] = fmaf(p, __uint_as_float(u.z & 0xffff0000u), acc[8*t+5]);
        acc[8*t+6] = fmaf(p, __uint_as_float(u.w << 16),         acc[8*t+6]);
        acc[8*t+7] = fmaf(p, __uint_as_float(u.w & 0xffff0000u), acc[8*t+7]);
      }
    }
    float invz = 1.0f / z2;
    float* op = out + ((size_t)(2 + bb) * C_) * HW + (size_t)hh * W_ + i;
    #pragma unroll
    for (int c = 0; c < C_; ++c)
      op[(size_t)c * HW] = fmaf(gamma3[c], acc[c] * invz, xr[(size_t)c * HW]);
  }
  __syncthreads();

  // Phase 5: grab own Q column (A still holds Q), then S -> A, bufR -> B
  float q[C_]; read_row(A[i], q);
  conv_to_lds(xr, trr, Wr1, 66, br1, beta1, yy, rr, 1, A[i]);   // S (bit-identical recompute)
  conv_to_lds(xr, rer, Wr2, 64, br2, gamma1, 0.f, 0.f, 0, B[i]); // bufR
  __syncthreads();

  // Phase 6: out_L[c,i] = x_l + beta3 * (sum_{j<=i} exp(s_ij - m1) * bufR[c,j]) / z1
  {
    float acc[C_];
    #pragma unroll
    for (int c = 0; c < C_; ++c) acc[c] = 0.f;
    for (int j = 0; j <= i; ++j) {
      float s = scale * dot_row_q(A[j], q);
      float p = __expf(s - m1);
      const uint4* r4 = (const uint4*)B[j];
      #pragma unroll
      for (int t = 0; t < 8; ++t) {
        uint4 u = r4[t];
        acc[8*t+0] = fmaf(p, __uint_as_float(u.x << 16),         acc[8*t+0]);
        acc[8*t+1] = fmaf(p, __uint_as_float(u.x & 0xffff0000u), acc[8*t+1]);
        acc[8*t+2] = fmaf(p, __uint_as_float(u.y << 16),         acc[8*t+2]);
        acc[8*t+3] = fmaf(p, __uint_as_float(u.y & 0xffff0000u), acc[8*t+3]);
        acc[8*t+4] = fmaf(p, __uint_as_float(u.z << 16),         acc[8*t+4]);
        acc[8*t+5] = fmaf(p, __uint_as_float(u.z & 0xffff0000u), acc[8*t+5]);
        acc[8*t+6] = fmaf(p, __uint_as_float(u.w << 16),         acc[8*t+6]);
        acc[8*t+7] = fmaf(p, __uint_as_float(u.w & 0xffff0000u), acc[8*t+7]);
      }
    }
    float invz = 1.0f / z1;
    float* op = out + ((size_t)bb * C_) * HW + (size_t)hh * W_ + i;
    #pragma unroll
    for (int c = 0; c < C_; ++c)
      op[(size_t)c * HW] = fmaf(beta3[c], acc[c] * invz, xl[(size_t)c * HW]);
  }
}

extern "C" void kernel_launch(void* const* d_in, const int* in_sizes, int n_in,
                              void* d_out, int out_size, void* d_ws, size_t ws_size,
                              hipStream_t stream) {
  const float* x       = (const float*)d_in[0];
  const float* res_enc = (const float*)d_in[1];
  const float* tr_feat = (const float*)d_in[2];
  const float* Wl1     = (const float*)d_in[3];
  const float* bl1     = (const float*)d_in[4];
  const float* Wr1     = (const float*)d_in[5];
  const float* br1     = (const float*)d_in[6];
  const float* Wl2     = (const float*)d_in[7];
  const float* bl2     = (const float*)d_in[8];
  const float* Wr2     = (const float*)d_in[9];
  const float* br2     = (const float*)d_in[10];
  const float* beta1   = (const float*)d_in[11];
  const float* gamma1  = (const float*)d_in[12];
  const float* beta3   = (const float*)d_in[13];
  const float* gamma3  = (const float*)d_in[14];
  float* outp = (float*)d_out;

  dim3 grid(512);   // 2 batches x 256 rows
  dim3 block(256);
  SCAM_73151882985874_kernel<<<grid, block, 0, stream>>>(
      x, res_enc, tr_feat, Wl1, bl1, Wr1, br1, Wl2, bl2, Wr2, br2,
      beta1, gamma1, beta3, gamma3, outp);
}

// Round 2
// 86.530 us; speedup vs baseline: 9.5785x; 9.5785x over previous
//
#include <hip/hip_runtime.h>
#include <stdint.h>

#define HW 65536   // 256*256
#define C_ 64

typedef __attribute__((ext_vector_type(8))) short short8;
typedef __attribute__((ext_vector_type(4))) float f32x4;

#define MFMA(a, b, c) __builtin_amdgcn_mfma_f32_16x16x32_bf16((a), (b), (c), 0, 0, 0)

union U16x8 { uint4 q; short8 v; uint32_t u[4]; };

__device__ inline uint32_t pack_bf16(float lo, float hi) {
  uint32_t ul = __float_as_uint(lo), uh = __float_as_uint(hi);
  ul = (ul + 0x7fffu + ((ul >> 16) & 1u)) >> 16;
  uh = (uh + 0x7fffu + ((uh >> 16) & 1u)) >> 16;
  return ul | (uh << 16);
}
__device__ inline uint16_t bf16r(float f) {
  uint32_t u = __float_as_uint(f);
  return (uint16_t)((u + 0x7fffu + ((u >> 16) & 1u)) >> 16);
}
__device__ inline short8 ld8(const uint16_t* p) {
  U16x8 t; t.q = *(const uint4*)p; return t.v;
}
// [pixel][64 c] bf16 tile, XOR swizzle (16B granule) to kill 128B-stride bank conflicts
__device__ inline int pc_idx(int pixel, int c) {
  return (pixel * 64 + c) ^ ((pixel & 7) << 3);
}
// [c][256 j] bf16 tile (V layout), 16B-granule swizzle on 512B rows
__device__ inline int cj_idx(int c, int j) {
  return (c * 256 + j) ^ ((c & 7) << 3);
}

__global__ __launch_bounds__(512, 1) void SCAM_73151882985874_kernel(
    const float* __restrict__ x, const float* __restrict__ res_enc,
    const float* __restrict__ tr_feat,
    const float* __restrict__ Wl1, const float* __restrict__ bl1,
    const float* __restrict__ Wr1, const float* __restrict__ br1,
    const float* __restrict__ Wl2, const float* __restrict__ bl2,
    const float* __restrict__ Wr2, const float* __restrict__ br2,
    const float* __restrict__ beta1, const float* __restrict__ gamma1,
    const float* __restrict__ beta3, const float* __restrict__ gamma3,
    float* __restrict__ out)
{
  __shared__ uint16_t sX[16384];   // staged input (bf16, [pixel][c])
  __shared__ uint16_t sQ[16384];   // Q*0.125  ([pixel][c])
  __shared__ uint16_t sS[16384];   // S        ([pixel][c])
  __shared__ uint16_t sV[16384];   // bufL then bufR ([c][j])
  __shared__ uint16_t sP[10240];   // per-wave P tiles: 8 x [32][40]

  const int tid = threadIdx.x;
  const int wid = tid >> 6, lane = tid & 63, g = lane >> 4, li = lane & 15;
  const int bb = blockIdx.x >> 8, hh = blockIdx.x & 255;
  const float yy = (float)hh * (2.0f / 255.0f) - 1.0f;
  const float rr = fabsf(yy - 0.5f);

  const size_t rowoff = (size_t)hh * 256;
  const float* xl  = x + ((size_t)bb * C_) * HW + rowoff;
  const float* xr  = x + ((size_t)(2 + bb) * C_) * HW + rowoff;
  const float* trl = tr_feat + ((size_t)bb * C_) * HW + rowoff;
  const float* trr = tr_feat + ((size_t)(2 + bb) * C_) * HW + rowoff;
  const float* rel = res_enc + ((size_t)bb * C_) * HW + rowoff;
  const float* rer = res_enc + ((size_t)(2 + bb) * C_) * HW + rowoff;
  float* outL = out + ((size_t)bb * C_) * HW + rowoff;
  float* outR = out + ((size_t)(2 + bb) * C_) * HW + rowoff;

  uint16_t* Pw = &sP[wid * 1280];

  // ---- stage global f32 [c][w] -> LDS bf16 [pixel][c]
  auto stage = [&](const float* src) {
    int p = tid & 255, h = tid >> 8;
    #pragma unroll
    for (int cb = 0; cb < 4; ++cb) {
      int c0 = h * 32 + cb * 8;
      const float* s = src + (size_t)c0 * HW + p;
      U16x8 t;
      t.u[0] = pack_bf16(s[0],              s[(size_t)HW]);
      t.u[1] = pack_bf16(s[2 * (size_t)HW], s[3 * (size_t)HW]);
      t.u[2] = pack_bf16(s[4 * (size_t)HW], s[5 * (size_t)HW]);
      t.u[3] = pack_bf16(s[6 * (size_t)HW], s[7 * (size_t)HW]);
      *(uint4*)&sX[pc_idx(p, c0)] = t.q;
    }
  };

  // ---- 1x1 conv via MFMA: D[c_out, pixel] = W * X(staged). Two output styles.
  auto conv = [&](const float* Wm, int ldw, const float* bias, const float* mod,
                  const float* E, int coord, float qscale,
                  uint16_t* dstQ /*pc layout or nullptr*/, int toV) {
    short8 af[4][2];
    #pragma unroll
    for (int ct = 0; ct < 4; ++ct)
      #pragma unroll
      for (int kk = 0; kk < 2; ++kk) {
        const float* wr = Wm + (size_t)(ct * 16 + li) * ldw + kk * 32 + g * 8;
        U16x8 t;
        t.u[0] = pack_bf16(wr[0], wr[1]);
        t.u[1] = pack_bf16(wr[2], wr[3]);
        t.u[2] = pack_bf16(wr[4], wr[5]);
        t.u[3] = pack_bf16(wr[6], wr[7]);
        af[ct][kk] = t.v;
      }
    #pragma unroll
    for (int ptl = 0; ptl < 2; ++ptl) {
      int pix = (wid * 2 + ptl) * 16 + li;
      short8 bx0 = ld8(&sX[pc_idx(pix, g * 8)]);
      short8 bx1 = ld8(&sX[pc_idx(pix, 32 + g * 8)]);
      #pragma unroll
      for (int ct = 0; ct < 4; ++ct) {
        f32x4 acc = {0.f, 0.f, 0.f, 0.f};
        acc = MFMA(af[ct][0], bx0, acc);
        acc = MFMA(af[ct][1], bx1, acc);
        uint16_t pk[4];
        #pragma unroll
        for (int r = 0; r < 4; ++r) {
          int c = ct * 16 + 4 * g + r;
          float b = bias[c];
          if (coord) b += Wm[(size_t)c * ldw + 64] * yy + Wm[(size_t)c * ldw + 65] * rr;
          float v = (acc[r] + b + mod[c] * E[(size_t)c * HW + pix]) * qscale;
          pk[r] = bf16r(v);
          if (toV) sV[cj_idx(c, pix)] = pk[r];
        }
        if (!toV) {
          uint2 w2;
          w2.x = (uint32_t)pk[0] | ((uint32_t)pk[1] << 16);
          w2.y = (uint32_t)pk[2] | ((uint32_t)pk[3] << 16);
          *(uint2*)&dstQ[pc_idx(pix, ct * 16 + 4 * g)] = w2;
        }
      }
    }
  };

  // ================= conv pipeline =================
  stage(xl);
  __syncthreads();
  conv(Wl1, 66, bl1, beta1, trl, 1, 0.125f, sQ, 0);  // Q (scaled)
  conv(Wl2, 64, bl2, gamma1, rel, 0, 1.0f, nullptr, 1);  // bufL -> sV
  __syncthreads();
  stage(xr);
  __syncthreads();
  conv(Wr1, 66, br1, beta1, trr, 1, 1.0f, sS, 0);    // S
  __syncthreads();

  // ================= PASS 2: out_R (uses bufL in sV); keep i >= j =================
  {
    const int j0 = wid * 32;
    short8 bS[2][2];
    #pragma unroll
    for (int jt = 0; jt < 2; ++jt)
      #pragma unroll
      for (int kk = 0; kk < 2; ++kk)
        bS[jt][kk] = ld8(&sS[pc_idx(j0 + jt * 16 + li, kk * 32 + g * 8)]);

    f32x4 acc[4][2];
    #pragma unroll
    for (int ct = 0; ct < 4; ++ct) { acc[ct][0] = (f32x4){0,0,0,0}; acc[ct][1] = (f32x4){0,0,0,0}; }
    float zp0 = 0.f, zp1 = 0.f;

    for (int ip = wid; ip < 8; ++ip) {
      #pragma unroll
      for (int itl = 0; itl < 2; ++itl) {
        short8 aQ0 = ld8(&sQ[pc_idx(ip * 32 + itl * 16 + li, g * 8)]);
        short8 aQ1 = ld8(&sQ[pc_idx(ip * 32 + itl * 16 + li, 32 + g * 8)]);
        #pragma unroll
        for (int jt = 0; jt < 2; ++jt) {
          f32x4 s = {0.f, 0.f, 0.f, 0.f};
          s = MFMA(aQ0, bS[jt][0], s);
          s = MFMA(aQ1, bS[jt][1], s);
          int jj = j0 + jt * 16 + li;
          float ps = 0.f; uint16_t pk[4];
          #pragma unroll
          for (int r = 0; r < 4; ++r) {
            int ii = ip * 32 + itl * 16 + 4 * g + r;
            float p = (ii >= jj) ? __expf(s[r]) : 0.f;
            ps += p; pk[r] = bf16r(p);
          }
          if (jt == 0) zp0 += ps; else zp1 += ps;
          uint2 w2;
          w2.x = (uint32_t)pk[0] | ((uint32_t)pk[1] << 16);
          w2.y = (uint32_t)pk[2] | ((uint32_t)pk[3] << 16);
          *(uint2*)&Pw[(jt * 16 + li) * 40 + itl * 16 + 4 * g] = w2;
        }
      }
      #pragma unroll
      for (int jt = 0; jt < 2; ++jt) {
        short8 bP = ld8(&Pw[(jt * 16 + li) * 40 + 8 * g]);
        #pragma unroll
        for (int ct = 0; ct < 4; ++ct) {
          short8 aV = ld8(&sV[cj_idx(ct * 16 + li, ip * 32 + 8 * g)]);
          acc[ct][jt] = MFMA(aV, bP, acc[ct][jt]);
        }
      }
    }
    zp0 += __shfl_xor(zp0, 16); zp0 += __shfl_xor(zp0, 32);
    zp1 += __shfl_xor(zp1, 16); zp1 += __shfl_xor(zp1, 32);
    #pragma unroll
    for (int jt = 0; jt < 2; ++jt) {
      float invz = 1.0f / (jt == 0 ? zp0 : zp1);
      int j = j0 + jt * 16 + li;
      #pragma unroll
      for (int ct = 0; ct < 4; ++ct)
        #pragma unroll
        for (int r = 0; r < 4; ++r) {
          int c = ct * 16 + 4 * g + r;
          outR[(size_t)c * HW + j] =
              fmaf(gamma3[c], acc[ct][jt][r] * invz, xr[(size_t)c * HW + j]);
        }
    }
  }
  __syncthreads();
  conv(Wr2, 64, br2, gamma1, rer, 0, 1.0f, nullptr, 1);  // bufR -> sV (reads sX=XR)
  __syncthreads();

  // ================= PASS 1: out_L (uses bufR in sV); keep j <= i =================
  {
    const int i0 = wid * 32;
    short8 bQ[2][2];
    #pragma unroll
    for (int itl = 0; itl < 2; ++itl)
      #pragma unroll
      for (int kk = 0; kk < 2; ++kk)
        bQ[itl][kk] = ld8(&sQ[pc_idx(i0 + itl * 16 + li, kk * 32 + g * 8)]);

    f32x4 acc[4][2];
    #pragma unroll
    for (int ct = 0; ct < 4; ++ct) { acc[ct][0] = (f32x4){0,0,0,0}; acc[ct][1] = (f32x4){0,0,0,0}; }
    float zp0 = 0.f, zp1 = 0.f;

    for (int jp = 0; jp <= wid; ++jp) {
      #pragma unroll
      for (int jt = 0; jt < 2; ++jt) {
        short8 aS0 = ld8(&sS[pc_idx(jp * 32 + jt * 16 + li, g * 8)]);
        short8 aS1 = ld8(&sS[pc_idx(jp * 32 + jt * 16 + li, 32 + g * 8)]);
        #pragma unroll
        for (int itl = 0; itl < 2; ++itl) {
          f32x4 s = {0.f, 0.f, 0.f, 0.f};
          s = MFMA(aS0, bQ[itl][0], s);
          s = MFMA(aS1, bQ[itl][1], s);
          int ii = i0 + itl * 16 + li;
          float ps = 0.f; uint16_t pk[4];
          #pragma unroll
          for (int r = 0; r < 4; ++r) {
            int jj = jp * 32 + jt * 16 + 4 * g + r;
            float p = (jj <= ii) ? __expf(s[r]) : 0.f;
            ps += p; pk[r] = bf16r(p);
          }
          if (itl == 0) zp0 += ps; else zp1 += ps;
          uint2 w2;
          w2.x = (uint32_t)pk[0] | ((uint32_t)pk[1] << 16);
          w2.y = (uint32_t)pk[2] | ((uint32_t)pk[3] << 16);
          *(uint2*)&Pw[(itl * 16 + li) * 40 + jt * 16 + 4 * g] = w2;
        }
      }
      #pragma unroll
      for (int itl = 0; itl < 2; ++itl) {
        short8 bP = ld8(&Pw[(itl * 16 + li) * 40 + 8 * g]);
        #pragma unroll
        for (int ct = 0; ct < 4; ++ct) {
          short8 aV = ld8(&sV[cj_idx(ct * 16 + li, jp * 32 + 8 * g)]);
          acc[ct][itl] = MFMA(aV, bP, acc[ct][itl]);
        }
      }
    }
    zp0 += __shfl_xor(zp0, 16); zp0 += __shfl_xor(zp0, 32);
    zp1 += __shfl_xor(zp1, 16); zp1 += __shfl_xor(zp1, 32);
    #pragma unroll
    for (int itl = 0; itl < 2; ++itl) {
      float invz = 1.0f / (itl == 0 ? zp0 : zp1);
      int i = i0 + itl * 16 + li;
      #pragma unroll
      for (int ct = 0; ct < 4; ++ct)
        #pragma unroll
        for (int r = 0; r < 4; ++r) {
          int c = ct * 16 + 4 * g + r;
          outL[(size_t)c * HW + i] =
              fmaf(beta3[c], acc[ct][itl][r] * invz, xl[(size_t)c * HW + i]);
        }
    }
  }
}

extern "C" void kernel_launch(void* const* d_in, const int* in_sizes, int n_in,
                              void* d_out, int out_size, void* d_ws, size_t ws_size,
                              hipStream_t stream) {
  const float* x       = (const float*)d_in[0];
  const float* res_enc = (const float*)d_in[1];
  const float* tr_feat = (const float*)d_in[2];
  const float* Wl1     = (const float*)d_in[3];
  const float* bl1     = (const float*)d_in[4];
  const float* Wr1     = (const float*)d_in[5];
  const float* br1     = (const float*)d_in[6];
  const float* Wl2     = (const float*)d_in[7];
  const float* bl2     = (const float*)d_in[8];
  const float* Wr2     = (const float*)d_in[9];
  const float* br2     = (const float*)d_in[10];
  const float* beta1   = (const float*)d_in[11];
  const float* gamma1  = (const float*)d_in[12];
  const float* beta3   = (const float*)d_in[13];
  const float* gamma3  = (const float*)d_in[14];
  float* outp = (float*)d_out;

  dim3 grid(512);    // 2 left-batches x 256 rows
  dim3 block(512);   // 8 waves
  SCAM_73151882985874_kernel<<<grid, block, 0, stream>>>(
      x, res_enc, tr_feat, Wl1, bl1, Wr1, br1, Wl2, bl2, Wr2, br2,
      beta1, gamma1, beta3, gamma3, outp);
}